// Round 3
// baseline (156.933 us; speedup 1.0000x reference)
//
#include <hip/hip_runtime.h>
#include <math.h>

// GLIF forward scan. T=64, B=128, N=2048 (derived at runtime from in_sizes).
// All recurrence math in float64: output is 0/1 spikes with threshold 2e-2,
// one flip = fail. f64 error ~1e-16 vs closest spike margin ~1e-7 => safe
// even under FMA contraction/reassociation (round-1 absmax was exactly 0.0).
//
// Memory floor: tx 67 MB read + out 67 MB write = ~21 us @ 6.3 TB/s.
// Round-3: 4 neurons/thread, native-vector float4 nontemporal streams
// (HIP float4 is a struct — the builtin needs ext_vector_type), 1-ahead
// software prefetch of x and icoef to keep loads in flight across the
// serial T-chain.

typedef float  fx4 __attribute__((ext_vector_type(4)));
typedef double dx2 __attribute__((ext_vector_type(2)));

__device__ __forceinline__ double dsig(double x) {
    return 1.0 / (1.0 + exp(-x));
}

// Precompute kernel: one thread per (t,n) element of icoef; threads with
// i < N additionally compute the per-n constants.
// ws layout (doubles): [0,N) decay_v | [N,2N) leak_term | [2N,3N) reset_w
//                      | [3N,4N) thr | [4N,5N) ga | [5N, 5N+T*N) icoef
__global__ void glif_pre_kernel(const float* __restrict__ alpha,
                                const float* __restrict__ beta,
                                const float* __restrict__ gamma,
                                const float* __restrict__ tau,
                                const float* __restrict__ Vth,
                                const float* __restrict__ leak,
                                const float* __restrict__ reVth,
                                const float* __restrict__ conduct,
                                double* __restrict__ wsd,
                                int N, int TN) {
    int i = blockIdx.x * blockDim.x + threadIdx.x;
    if (i >= TN) return;
    int n = i % N;
    double be = dsig((double)beta[n]);
    double cs = dsig((double)conduct[i]);
    wsd[5 * N + i] = 1.0 - be * (1.0 - cs);  // icoef[t][n]
    if (i < N) {
        double al     = dsig((double)alpha[i]);
        double ga     = dsig((double)gamma[i]);
        double tau_s  = dsig((double)tau[i]);
        double vth_s  = dsig((double)Vth[i]);
        double leak_s = dsig((double)leak[i]);
        double rev_s  = dsig((double)reVth[i]);
        wsd[0 * N + i] = 1.0 - al * (1.0 - tau_s);  // decay_v
        wsd[1 * N + i] = (1.0 - al) * leak_s;       // leak_term
        wsd[2 * N + i] = (1.0 - ga) * rev_s;        // reset_w
        wsd[3 * N + i] = vth_s;                     // thr
        wsd[4 * N + i] = ga;                        // ga
    }
}

// Main scan: one thread per 4 adjacent neurons (float4 global access),
// sequential loop over T with 1-ahead prefetch of x and icoef.
__global__ __launch_bounds__(256) void glif_main4_kernel(
        const float* __restrict__ tx,
        const double* __restrict__ wsd,
        float* __restrict__ out,
        int T, int B, int N) {
    const int quar = N >> 2;
    const int idx = blockIdx.x * blockDim.x + threadIdx.x;
    if (idx >= B * quar) return;
    const int b = idx / quar;
    const int n = (idx - b * quar) << 2;

    double dv[4], lt[4], rw[4], th[4], omga[4];
#pragma unroll
    for (int j = 0; j < 4; ++j) {
        dv[j]   = wsd[0 * N + n + j];
        lt[j]   = wsd[1 * N + n + j];
        rw[j]   = wsd[2 * N + n + j];
        th[j]   = wsd[3 * N + n + j];
        omga[j] = 1.0 - wsd[4 * N + n + j];  // (1 - ga); exact since ga*1 == ga
    }
    const double* icp = wsd + 5 * N + n;

    double v[4] = {0.0, 0.0, 0.0, 0.0};
    bool y[4] = {false, false, false, false};

    const size_t bn = (size_t)b * N + n;
    const float* txp = tx + bn;
    float* op = out + bn;
    const size_t stride = (size_t)B * N;

    // Prefetch t=0
    fx4 x = __builtin_nontemporal_load((const fx4*)txp);
    dx2 icA = *(const dx2*)icp;
    dx2 icB = *(const dx2*)(icp + 2);

#pragma unroll 4
    for (int t = 0; t < T; ++t) {
        fx4 xn;
        dx2 icAn, icBn;
        if (t + 1 < T) {  // wave-uniform branch; issues next loads before compute
            xn   = __builtin_nontemporal_load((const fx4*)(txp + stride));
            icAn = *(const dx2*)(icp + N);
            icBn = *(const dx2*)(icp + N + 2);
        }

        const double xs[4] = {(double)x.x, (double)x.y, (double)x.z, (double)x.w};
        const double ic[4] = {icA.x, icA.y, icB.x, icB.y};

        fx4 ov;
#pragma unroll
        for (int j = 0; j < 4; ++j) {
            const double I = xs[j] * ic[j];
            const double m = y[j] ? omga[j] : 1.0;  // (1 - ga*y), exact for y in {0,1}
            const double r = y[j] ? rw[j] : 0.0;    // reset_w*y, exact
            v[j] = dv[j] * v[j] * m - lt[j] + I - r;
            y[j] = v[j] > th[j];
            ov[j] = y[j] ? 1.0f : 0.0f;
        }
        __builtin_nontemporal_store(ov, (fx4*)op);

        x = xn; icA = icAn; icB = icBn;
        txp += stride;
        op += stride;
        icp += N;
    }
}

// Fallback (only if ws too small or N not divisible by 4): computes all
// sigmoids inline per thread, 2 neurons/thread. Same f64 expression tree.
__global__ __launch_bounds__(256) void glif_main_inline_kernel(
        const float* __restrict__ tx,
        const float* __restrict__ alpha,
        const float* __restrict__ beta,
        const float* __restrict__ gamma,
        const float* __restrict__ tau,
        const float* __restrict__ Vth,
        const float* __restrict__ leak,
        const float* __restrict__ reVth,
        const float* __restrict__ conduct,
        float* __restrict__ out,
        int T, int B, int N) {
    const int half = N >> 1;
    const int idx = blockIdx.x * blockDim.x + threadIdx.x;
    if (idx >= B * half) return;
    const int b = idx / half;
    const int n = (idx - b * half) << 1;

    const double al0 = dsig((double)alpha[n]), al1 = dsig((double)alpha[n + 1]);
    const double ga0 = dsig((double)gamma[n]), ga1 = dsig((double)gamma[n + 1]);
    const double be0 = dsig((double)beta[n]),  be1 = dsig((double)beta[n + 1]);
    const double ts0 = dsig((double)tau[n]),   ts1 = dsig((double)tau[n + 1]);
    const double th0 = dsig((double)Vth[n]),   th1 = dsig((double)Vth[n + 1]);
    const double ls0 = dsig((double)leak[n]),  ls1 = dsig((double)leak[n + 1]);
    const double rs0 = dsig((double)reVth[n]), rs1 = dsig((double)reVth[n + 1]);
    const double dv0 = 1.0 - al0 * (1.0 - ts0), dv1 = 1.0 - al1 * (1.0 - ts1);
    const double lt0 = (1.0 - al0) * ls0,       lt1 = (1.0 - al1) * ls1;
    const double rw0 = (1.0 - ga0) * rs0,       rw1 = (1.0 - ga1) * rs1;
    const double om_ga0 = 1.0 - ga0, om_ga1 = 1.0 - ga1;

    double v0 = 0.0, v1 = 0.0;
    bool y0 = false, y1 = false;

    const size_t bn = (size_t)b * N + n;
    const float* txp = tx + bn;
    float* op = out + bn;
    const float* cp = conduct + n;
    const size_t strideTx = (size_t)B * N;

    for (int t = 0; t < T; ++t) {
        const float2 x = *(const float2*)txp;
        const double ic0 = 1.0 - be0 * (1.0 - dsig((double)cp[0]));
        const double ic1 = 1.0 - be1 * (1.0 - dsig((double)cp[1]));

        const double I0 = (double)x.x * ic0;
        const double m0 = y0 ? om_ga0 : 1.0;
        const double r0 = y0 ? rw0 : 0.0;
        v0 = dv0 * v0 * m0 - lt0 + I0 - r0;
        y0 = v0 > th0;

        const double I1 = (double)x.y * ic1;
        const double m1 = y1 ? om_ga1 : 1.0;
        const double r1 = y1 ? rw1 : 0.0;
        v1 = dv1 * v1 * m1 - lt1 + I1 - r1;
        y1 = v1 > th1;

        float2 o;
        o.x = y0 ? 1.0f : 0.0f;
        o.y = y1 ? 1.0f : 0.0f;
        *(float2*)op = o;

        txp += strideTx;
        op += strideTx;
        cp += N;
    }
}

extern "C" void kernel_launch(void* const* d_in, const int* in_sizes, int n_in,
                              void* d_out, int out_size, void* d_ws, size_t ws_size,
                              hipStream_t stream) {
    const float* tx      = (const float*)d_in[0];
    const float* alpha   = (const float*)d_in[1];
    const float* beta    = (const float*)d_in[2];
    const float* gamma   = (const float*)d_in[3];
    const float* tau     = (const float*)d_in[4];
    const float* Vth     = (const float*)d_in[5];
    const float* leak    = (const float*)d_in[6];
    const float* reVth   = (const float*)d_in[7];
    const float* conduct = (const float*)d_in[8];
    float* out = (float*)d_out;

    const int N  = in_sizes[1];        // 2048
    const int TN = in_sizes[8];        // T*N = 131072
    const int T  = TN / N;             // 64
    const int B  = in_sizes[0] / TN;   // 128

    const size_t needed = (size_t)(5 * N + TN) * sizeof(double);
    if (ws_size >= needed && (N & 3) == 0) {
        double* wsd = (double*)d_ws;
        const int preBlocks = (TN + 255) / 256;
        glif_pre_kernel<<<preBlocks, 256, 0, stream>>>(
            alpha, beta, gamma, tau, Vth, leak, reVth, conduct, wsd, N, TN);
        const int total = B * (N >> 2);
        glif_main4_kernel<<<(total + 255) / 256, 256, 0, stream>>>(
            tx, wsd, out, T, B, N);
    } else {
        const int total = B * (N >> 1);
        glif_main_inline_kernel<<<(total + 255) / 256, 256, 0, stream>>>(
            tx, alpha, beta, gamma, tau, Vth, leak, reVth, conduct,
            out, T, B, N);
    }
}